// Round 2
// baseline (5373.735 us; speedup 1.0000x reference)
//
#include <hip/hip_runtime.h>
#include <hip/hip_bf16.h>

// N=512, T=64, D=512, H=512, 4H=2048, K = D+2H = 1536
// Round 6: persistent kernel via REGULAR launch + manual device-scope grid
// barrier (coop launch silently failed in round 5 -> zeros). Numerics moved
// to bf16: B = exact bf16 weights (inputs are bf16; detector-guarded fp32
// fallback rounds W to bf16, err ~2^-9 -> ok vs 1.86e-2 threshold), A = bf16
// hi+lo split (~2^-17). x-region staged directly from x (exact bf16, hi only)
// with pre-swizzled source addresses. 4-buffer 2-ahead global_load_lds
// pipeline with exact counted vmcnt. B resident in 192 VGPRs/wave.
#define NBATCH 512
#define TS   64
#define KTOT 1536

typedef short bf16x8 __attribute__((ext_vector_type(8)));
typedef float f32x4 __attribute__((ext_vector_type(4)));

__device__ __forceinline__ unsigned short f2bf(float v) {
    union { float f; unsigned u; } c; c.f = v;
    unsigned r = (c.u + 0x7fffu + ((c.u >> 16) & 1u)) >> 16;  // RTNE
    return (unsigned short)r;
}
__device__ __forceinline__ float bf2f(unsigned short b) {
    union { unsigned u; float f; } c; c.u = (unsigned)b << 16; return c.f;
}

// Load input element i as float, from either a bf16 or fp32 buffer.
__device__ __forceinline__ float ldin(const void* p, size_t i, int isbf) {
    if (isbf) return bf2f(((const unsigned short*)p)[i]);
    return ((const float*)p)[i];
}

// Detect input dtype: sample even-index ushorts of x, decode as bf16.
__global__ void detect_dtype(const void* x, int* flag) {
    __shared__ int bad;
    if (threadIdx.x == 0) bad = 0;
    __syncthreads();
    const unsigned short* u = (const unsigned short*)x;
    int mybad = 0;
    for (int k = 0; k < 16; ++k) {
        size_t i = (size_t)(threadIdx.x + k * 256) * 1987 + 3;
        float v = bf2f(u[2 * i]);
        if (!(fabsf(v) < 1000.0f)) mybad = 1;
    }
    if (mybad) atomicOr(&bad, 1);
    __syncthreads();
    if (threadIdx.x == 0) *flag = (bad == 0) ? 1 : 0;
}

// ---------------- one-time setup ----------------

// WT [c][k] bf16 of W; c in [0,2048), k in [0,1536): k<512 Wx, <1024 Wh, else Wattn
__global__ __launch_bounds__(256) void build_wT(const void* __restrict__ Wx,
                                                const void* __restrict__ Wh,
                                                const void* __restrict__ Wattn,
                                                const int* __restrict__ flagp,
                                                unsigned short* __restrict__ WT) {
    int isbf = *flagp;
    __shared__ float tile[64][65];
    int k0 = blockIdx.x * 64;   // 24 blocks
    int c0 = blockIdx.y * 64;   // 32 blocks
    int tid = threadIdx.x;
    int cl = tid & 63;
    int kr = tid >> 6;
#pragma unroll
    for (int r = 0; r < 16; ++r) {
        int kl = kr * 16 + r;
        int k = k0 + kl;
        const void* src;
        size_t roff;
        if (k < 512)       { src = Wx;    roff = (size_t)k * 2048; }
        else if (k < 1024) { src = Wh;    roff = (size_t)(k - 512) * 2048; }
        else               { src = Wattn; roff = (size_t)(k - 1024) * 2048; }
        tile[kl][cl] = ldin(src, roff + c0 + cl, isbf);
    }
    __syncthreads();
    int kl2 = tid & 63;
    int cr = tid >> 6;
#pragma unroll
    for (int r = 0; r < 16; ++r) {
        int cl2 = cr * 16 + r;
        WT[(size_t)(c0 + cl2) * KTOT + k0 + kl2] = f2bf(tile[kl2][cl2]);
    }
}

// h0 = c0 = mean over 16 spatial positions of A[n,h,:,:]
__global__ __launch_bounds__(256) void init_state(const void* __restrict__ A,
                                                  const int* __restrict__ flagp,
                                                  float* __restrict__ h,
                                                  float* __restrict__ c) {
    int isbf = *flagp;
    int n = blockIdx.x;
    int tid = threadIdx.x;
#pragma unroll
    for (int j = 0; j < 2; ++j) {
        int hh = tid * 2 + j;
        size_t base = ((size_t)n * 512 + hh) * 16;
        float s = 0.f;
#pragma unroll
        for (int p = 0; p < 16; ++p) s += ldin(A, base + p, isbf);
        s *= (1.0f / 16.0f);
        h[n * 512 + hh] = s;
        c[n * 512 + hh] = s;
    }
}

// ---------------- manual grid barrier (device-scope) ----------------
// bar[(g)<<5] for g in 0..7: padded arrival counters (monotonic).
// bar[256]: release epoch, stored by root block 0. Zeroed per launch.
__device__ __forceinline__ void gbar_arrive(unsigned* bar, int bid) {
    __syncthreads();   // drains each wave's vmem; orders all block stores
    if (threadIdx.x == 0)
        __hip_atomic_fetch_add(&bar[(bid & 7) << 5], 1u, __ATOMIC_ACQ_REL,
                               __HIP_MEMORY_SCOPE_AGENT);
}
__device__ __forceinline__ void gbar_wait(unsigned* bar, int bid, unsigned epoch) {
    if (threadIdx.x == 0) {
        if (bid == 0) {
#pragma unroll 1
            for (int g = 0; g < 8; ++g) {
                int guard = 0;
                while (__hip_atomic_load(&bar[g << 5], __ATOMIC_ACQUIRE,
                                         __HIP_MEMORY_SCOPE_AGENT) < epoch * 32u) {
                    __builtin_amdgcn_s_sleep(1);
                    if (++guard > (1 << 20)) break;   // fail loud, not hung
                }
            }
            __hip_atomic_store(&bar[256], epoch, __ATOMIC_RELEASE,
                               __HIP_MEMORY_SCOPE_AGENT);
        } else {
            int guard = 0;
            while (__hip_atomic_load(&bar[256], __ATOMIC_ACQUIRE,
                                     __HIP_MEMORY_SCOPE_AGENT) < epoch) {
                __builtin_amdgcn_s_sleep(1);
                if (++guard > (1 << 20)) break;
            }
        }
    }
    __syncthreads();
}

// ---------------- helpers for the persistent kernel ----------------

__device__ __forceinline__ void sstore(unsigned short* hi, unsigned short* lo,
                                       int idx, float v) {
    unsigned short h = f2bf(v);
    hi[idx] = h;
    lo[idx] = f2bf(v - bf2f(h));
}

// Load 16 consecutive input elements (one A spatial row) as floats.
__device__ __forceinline__ void ldA16(const void* A, size_t eb, int isbf, float* av) {
    if (isbf) {
        const uint4* p = (const uint4*)((const unsigned short*)A + eb);
        uint4 a = p[0], b = p[1];
        unsigned int w[8] = {a.x, a.y, a.z, a.w, b.x, b.y, b.z, b.w};
#pragma unroll
        for (int q = 0; q < 8; ++q) {
            union { unsigned int u; float f; } lo, hi;
            lo.u = (w[q] & 0xffffu) << 16;
            hi.u = w[q] & 0xffff0000u;
            av[2 * q]     = lo.f;
            av[2 * q + 1] = hi.f;
        }
    } else {
        const float4* p = (const float4*)((const float*)A + eb);
#pragma unroll
        for (int q = 0; q < 4; ++q) {
            float4 v = p[q];
            av[4 * q + 0] = v.x; av[4 * q + 1] = v.y;
            av[4 * q + 2] = v.z; av[4 * q + 3] = v.w;
        }
    }
}

__device__ __forceinline__ void gload_lds16(const void* g, void* l) {
    __builtin_amdgcn_global_load_lds(
        (const __attribute__((address_space(1))) void*)g,
        (__attribute__((address_space(3))) void*)l, 16, 0, 0);
}

// Stage one 64-row x 128-elem bf16 chunk of Acat (pre-swizzled in memory).
// WITHLO: 8 vmem ops, else 4.
template <bool WITHLO>
__device__ __forceinline__ void stage_acat(const unsigned short* __restrict__ Ahi,
                                           const unsigned short* __restrict__ Alo,
                                           char (*AbH)[16384], char (*AbL)[16384],
                                           int buf, int ch, int n0, int wave, int lane) {
    const size_t colb = (size_t)((lane & 15) * 16);
    const int rg0 = wave * 16 + (lane >> 4);
#pragma unroll
    for (int i = 0; i < 4; ++i) {
        const int rg = rg0 + i * 4;
        const size_t so = (size_t)(n0 + rg) * 3072 + (size_t)ch * 256 + colb;
        gload_lds16((const char*)Ahi + so, &AbH[buf][(wave * 4 + i) * 1024]);
        if (WITHLO)
            gload_lds16((const char*)Alo + so, &AbL[buf][(wave * 4 + i) * 1024]);
    }
}

// Stage one x-chunk directly from bf16 input x, source col pre-swizzled
// so linear LDS + swizzled ds_read is consistent. 4 vmem ops.
__device__ __forceinline__ void stage_x(const char* __restrict__ xb,
                                        char (*AbH)[16384],
                                        int buf, int ch, int n0, int t,
                                        int wave, int lane) {
    const int rg0 = wave * 16 + (lane >> 4);
#pragma unroll
    for (int i = 0; i < 4; ++i) {
        const int rg = rg0 + i * 4;
        const int n = n0 + rg;
        const size_t so = (size_t)n * 65536 + (size_t)t * 1024 + (size_t)ch * 256
                        + (size_t)(((lane & 15) * 16) ^ ((n & 7) << 4));
        gload_lds16(xb + so, &AbH[buf][(wave * 4 + i) * 1024]);
    }
}

// ---------------- the persistent fused kernel ----------------
// grid = 256 x 256 (regular launch; 147 KB LDS forces 1 block/CU => all
// co-resident). block: m = bid&7 (64 rows), cs = bid>>3 (16 h-cols);
// wave w owns gate w; its B slice (16 cols x 1536 k bf16) lives in 192 VGPRs.
__global__ __launch_bounds__(256, 1) void fused_all(
    const void* __restrict__ x, const void* __restrict__ A,
    const unsigned short* __restrict__ WT, const void* __restrict__ bias,
    const int* __restrict__ flagp, float* __restrict__ h, float* __restrict__ c,
    unsigned short* __restrict__ Ahi, unsigned short* __restrict__ Alo,
    unsigned* __restrict__ bar, void* __restrict__ out)
{
    const int isbf = *flagp;
    const int tid  = threadIdx.x;
    const int lane = tid & 63;
    const int wave = tid >> 6;
    const int bid  = blockIdx.x;
    const int m    = bid & 7;
    const int cs   = bid >> 3;
    const int n0   = m * 64;
    const char* xb = (const char*)x;

    __shared__ __align__(16) char AbH[4][16384];   // 4-buffer A-hi staging
    __shared__ __align__(16) char AbL[4][16384];   // 4-buffer A-lo staging
    __shared__ float accX[4][64][16];              // gate exchange for epilogue
    __shared__ float wsum[4][16];                  // prep cross-wave reduce

    // ---- one-time: B fragments into registers (48 x bf16x8 = 192 VGPR) ----
    bf16x8 Bb[48];
    {
        const int col = wave * 512 + cs * 16 + (lane & 15);
        const unsigned short* wp = WT + (size_t)col * KTOT + (size_t)((lane >> 4) * 8);
#pragma unroll
        for (int kk = 0; kk < 48; ++kk) Bb[kk] = *(const bf16x8*)(wp + kk * 32);
    }

    // ---- one-time: epilogue constants ----
    const int ecol  = tid & 15;
    const int erow0 = (tid >> 4) * 4;
    const int hcol  = cs * 16 + ecol;
    const float bi  = ldin(bias, hcol,        isbf);
    const float bf_ = ldin(bias, 512 + hcol,  isbf);
    const float bo  = ldin(bias, 1024 + hcol, isbf);
    const float bg  = ldin(bias, 1536 + hcol, isbf);

    // ---- prep-phase constants: 2 rows per block, 128 threads per row ----
    const int prow = tid >> 7;
    const int ptl  = tid & 127;
    const int pn   = bid * 2 + prow;
    const int pw0  = prow * 2;
    const int sx   = (pn & 7) << 3;   // Acat element swizzle

#pragma unroll 1
    for (int t = 0; t < TS; ++t) {
        const unsigned ea = 2u * t + 1u, eb = 2u * t + 2u;

        // ============ P: attention + swizzled Acat (h, attn regions) ============
        {
            float part[16];
#pragma unroll
            for (int p = 0; p < 16; ++p) part[p] = 0.f;
#pragma unroll
            for (int j = 0; j < 4; ++j) {
                const int he = ptl + j * 128;
                const float hv = h[pn * 512 + he];
                float av[16];
                ldA16(A, ((size_t)pn * 512 + he) * 16, isbf, av);
#pragma unroll
                for (int p = 0; p < 16; ++p) part[p] += hv * av[p];
            }
#pragma unroll
            for (int off = 32; off > 0; off >>= 1) {
#pragma unroll
                for (int p = 0; p < 16; ++p) part[p] += __shfl_down(part[p], off, 64);
            }
            if (lane == 0) {
#pragma unroll
                for (int p = 0; p < 16; ++p) wsum[wave][p] = part[p];
            }
            __syncthreads();
            const float scale = 0.04419417382415922f;  // 1/sqrt(512)
            float sc[16], mx = -1e30f;
#pragma unroll
            for (int p = 0; p < 16; ++p) {
                sc[p] = (wsum[pw0][p] + wsum[pw0 + 1][p]) * scale;
                mx = fmaxf(mx, sc[p]);
            }
            float ssum = 0.f;
#pragma unroll
            for (int p = 0; p < 16; ++p) { sc[p] = __expf(sc[p] - mx); ssum += sc[p]; }
            const float inv = 1.0f / ssum;

            unsigned short* hrow = Ahi + (size_t)pn * KTOT;
            unsigned short* lrow = Alo + (size_t)pn * KTOT;
            const size_t xbase = ((size_t)pn * TS + t) * 512;
#pragma unroll
            for (int j = 0; j < 4; ++j) {
                const int he = ptl + j * 128;
                const float hv = h[pn * 512 + he];
                float av[16];
                ldA16(A, ((size_t)pn * 512 + he) * 16, isbf, av);
                float at = 0.f;
#pragma unroll
                for (int p = 0; p < 16; ++p) at += av[p] * sc[p];
                at *= inv;
                sstore(hrow, lrow, (512 + he) ^ sx,  hv);
                sstore(hrow, lrow, (1024 + he) ^ sx, at);
                if (!isbf)  // fp32 inputs: x must be converted into Acat (hi only)
                    hrow[he ^ sx] = f2bf(((const float*)x)[xbase + he]);
            }
        }

        // grid barrier (a); overlap x-chunk staging with the wait (bf16 mode:
        // x chunks are independent of prep).
        gbar_arrive(bar, bid);
        if (isbf) {
            stage_x(xb, AbH, 0, 0, n0, t, wave, lane);
            stage_x(xb, AbH, 1, 1, n0, t, wave, lane);
        }
        gbar_wait(bar, bid, ea);
        if (!isbf) {
            stage_acat<false>(Ahi, Alo, AbH, AbL, 0, 0, n0, wave, lane);
            stage_acat<false>(Ahi, Alo, AbH, AbL, 1, 1, n0, wave, lane);
        }

        // ============ G: GEMM (12 chunks, 2-ahead pipeline) ============
        f32x4 acc[4];
#pragma unroll
        for (int mi = 0; mi < 4; ++mi) acc[mi] = (f32x4){0.f, 0.f, 0.f, 0.f};

#pragma unroll
        for (int ch = 0; ch < 12; ++ch) {
            if (ch <= 9) {
                const int nc = ch + 2;
                if (nc < 4) {
                    if (isbf) stage_x(xb, AbH, nc & 3, nc, n0, t, wave, lane);
                    else      stage_acat<false>(Ahi, Alo, AbH, AbL, nc & 3, nc, n0, wave, lane);
                } else {
                    stage_acat<true>(Ahi, Alo, AbH, AbL, nc & 3, nc, n0, wave, lane);
                }
            }
            // counted waits: ops/chunk = 4 (ch<4), 8 (ch>=4); allow chunks
            // ch+1, ch+2 to stay in flight.
            if (ch == 0 || ch == 1 || ch == 10)
                asm volatile("s_waitcnt vmcnt(8)" ::: "memory");
            else if (ch == 2)
                asm volatile("s_waitcnt vmcnt(12)" ::: "memory");
            else if (ch == 11)
                asm volatile("s_waitcnt vmcnt(0)" ::: "memory");
            else
                asm volatile("s_waitcnt vmcnt(16)" ::: "memory");
            __builtin_amdgcn_sched_barrier(0);
            __builtin_amdgcn_s_barrier();
            __builtin_amdgcn_sched_barrier(0);

            const char* abh = (const char*)AbH[ch & 3];
            const char* abl = (const char*)AbL[ch & 3];
#pragma unroll
            for (int kl = 0; kl < 4; ++kl) {
                const int kk = ch * 4 + kl;
                const int kb = kl * 64 + ((lane >> 4) * 16);
                bf16x8 ah[4];
#pragma unroll
                for (int mi = 0; mi < 4; ++mi) {
                    const int row = mi * 16 + (lane & 15);
                    ah[mi] = *(const bf16x8*)(abh + row * 256 + (kb ^ ((row & 7) << 4)));
                }
#pragma unroll
                for (int mi = 0; mi < 4; ++mi)
                    acc[mi] = __builtin_amdgcn_mfma_f32_16x16x32_bf16(ah[mi], Bb[kk], acc[mi], 0, 0, 0);
                if (ch >= 4) {   // x region is exact bf16: no lo term
                    bf16x8 al[4];
#pragma unroll
                    for (int mi = 0; mi < 4; ++mi) {
                        const int row = mi * 16 + (lane & 15);
                        al[mi] = *(const bf16x8*)(abl + row * 256 + (kb ^ ((row & 7) << 4)));
                    }
#pragma unroll
                    for (int mi = 0; mi < 4; ++mi)
                        acc[mi] = __builtin_amdgcn_mfma_f32_16x16x32_bf16(al[mi], Bb[kk], acc[mi], 0, 0, 0);
                }
            }
        }

        // ---- cross-wave gate exchange + fused LSTM epilogue ----
#pragma unroll
        for (int mi = 0; mi < 4; ++mi) {
            const int row = mi * 16 + (lane >> 4) * 4;
#pragma unroll
            for (int j = 0; j < 4; ++j) accX[wave][row + j][lane & 15] = acc[mi][j];
        }
        __syncthreads();
#pragma unroll
        for (int j = 0; j < 4; ++j) {
            const int r = erow0 + j;
            const int n = n0 + r;
            const float xi = accX[0][r][ecol] + bi;
            const float xf = accX[1][r][ecol] + bf_;
            const float xo = accX[2][r][ecol] + bo;
            const float xg = accX[3][r][ecol] + bg;
            const float iv = 1.f / (1.f + __expf(-xi));
            const float fv = 1.f / (1.f + __expf(-xf));
            const float ov = 1.f / (1.f + __expf(-xo));
            const float gv = 1.f - 2.f / (__expf(2.f * xg) + 1.f);   // tanh
            const float cold = c[n * 512 + hcol];
            const float cnew = fv * cold + iv * gv;
            const float tc = 1.f - 2.f / (__expf(2.f * cnew) + 1.f); // tanh
            const float hnew = ov * tc;
            c[n * 512 + hcol] = cnew;
            h[n * 512 + hcol] = hnew;
            const size_t oidx = ((size_t)n * TS + t) * 512 + hcol;
            if (isbf) ((__hip_bfloat16*)out)[oidx] = __float2bfloat16(hnew);
            else      ((float*)out)[oidx] = hnew;
        }

        // grid barrier (b): h/c complete before next prep reads them.
        if (t != TS - 1) {
            gbar_arrive(bar, bid);
            gbar_wait(bar, bid, eb);
        }
    }
}

// ---------------- launch ----------------

extern "C" void kernel_launch(void* const* d_in, const int* in_sizes, int n_in,
                              void* d_out, int out_size, void* d_ws, size_t ws_size,
                              hipStream_t stream) {
    const void* x     = d_in[0];
    const void* A     = d_in[1];
    const void* Wx    = d_in[2];
    const void* Wh    = d_in[3];
    const void* Wattn = d_in[4];
    const void* bias  = d_in[5];

    char* ws = (char*)d_ws;
    const size_t WSZ = (size_t)2048 * KTOT * 2;  // 6291456 B
    const size_t ASZ = (size_t)NBATCH * KTOT * 2; // 1572864 B
    unsigned short* WT  = (unsigned short*)ws;
    unsigned short* Ahi = (unsigned short*)(ws + WSZ);
    unsigned short* Alo = (unsigned short*)(ws + WSZ + ASZ);
    float* hbuf = (float*)(ws + WSZ + 2 * ASZ);
    float* cbuf = (float*)(ws + WSZ + 2 * ASZ + 1048576);
    char*  misc = ws + WSZ + 2 * ASZ + 2 * 1048576;
    int* flag      = (int*)misc;
    unsigned* bar  = (unsigned*)(misc + 1024);   // 257 u32, zeroed below

    hipMemsetAsync(misc, 0, 4096, stream);
    detect_dtype<<<1, 256, 0, stream>>>(x, flag);
    build_wT<<<dim3(24, 32), 256, 0, stream>>>(Wx, Wh, Wattn, flag, WT);
    init_state<<<512, 256, 0, stream>>>(A, flag, hbuf, cbuf);
    fused_all<<<256, 256, 0, stream>>>(x, A, WT, bias, flag, hbuf, cbuf,
                                       Ahi, Alo, bar, d_out);
}

// Round 4
// 3976.418 us; speedup vs baseline: 1.3514x; 1.3514x over previous
//
#include <hip/hip_runtime.h>
#include <hip/hip_bf16.h>

// N=512, T=64, D=512, H=512, 4H=2048, K = D+2H = 1536
// Round 8: round-7 architecture (persistent kernel, K-split waves, relaxed
// spin barrier, conflict-free LDS staging) with hardening after the infra
// failure:
//  - barrier guards shortened to 1<<16 (worst-case whole-kernel ~2 s even if
//    every barrier breaks; normal arrival skew ~50 us << 2 ms min spin)
//  - wave-exact counted vmcnt (waves with 16-op chunks no longer over-wait)
//  - bf16 path: x-region chunks (kbase<512) DMA directly from input x;
//    prologue x-chunks issue BETWEEN barrier arrive and wait (step-
//    independent), hiding DMA issue under the spin; prep skips x copy.
#define NBATCH 512
#define TS   64
#define KTOT 1536

typedef short bf16x8 __attribute__((ext_vector_type(8)));
typedef float f32x4  __attribute__((ext_vector_type(4)));

__device__ __forceinline__ unsigned short f2bf(float v) {
    union { float f; unsigned u; } c; c.f = v;
    unsigned r = (c.u + 0x7fffu + ((c.u >> 16) & 1u)) >> 16;  // RTNE
    return (unsigned short)r;
}
__device__ __forceinline__ float bf2f(unsigned short b) {
    union { unsigned u; float f; } c; c.u = (unsigned)b << 16; return c.f;
}
__device__ __forceinline__ float ldin(const void* p, size_t i, int isbf) {
    if (isbf) return bf2f(((const unsigned short*)p)[i]);
    return ((const float*)p)[i];
}

// Detect input dtype: sample even-index ushorts of x, decode as bf16.
__global__ void detect_dtype(const void* x, int* flag) {
    __shared__ int bad;
    if (threadIdx.x == 0) bad = 0;
    __syncthreads();
    const unsigned short* u = (const unsigned short*)x;
    int mybad = 0;
    for (int k = 0; k < 16; ++k) {
        size_t i = (size_t)(threadIdx.x + k * 256) * 1987 + 3;
        float v = bf2f(u[2 * i]);
        if (!(fabsf(v) < 1000.0f)) mybad = 1;
    }
    if (mybad) atomicOr(&bad, 1);
    __syncthreads();
    if (threadIdx.x == 0) *flag = (bad == 0) ? 1 : 0;
}

// ---------------- one-time setup ----------------

// WT [c][k] bf16; c in [0,2048), k in [0,1536): k<512 Wx, <1024 Wh, else Wattn
__global__ __launch_bounds__(256) void build_wT(const void* __restrict__ Wx,
                                                const void* __restrict__ Wh,
                                                const void* __restrict__ Wattn,
                                                const int* __restrict__ flagp,
                                                unsigned short* __restrict__ WT) {
    int isbf = *flagp;
    __shared__ float tile[64][65];
    int k0 = blockIdx.x * 64;
    int c0 = blockIdx.y * 64;
    int tid = threadIdx.x;
    int cl = tid & 63;
    int kr = tid >> 6;
#pragma unroll
    for (int r = 0; r < 16; ++r) {
        int kl = kr * 16 + r;
        int k = k0 + kl;
        const void* src;
        size_t roff;
        if (k < 512)       { src = Wx;    roff = (size_t)k * 2048; }
        else if (k < 1024) { src = Wh;    roff = (size_t)(k - 512) * 2048; }
        else               { src = Wattn; roff = (size_t)(k - 1024) * 2048; }
        tile[kl][cl] = ldin(src, roff + c0 + cl, isbf);
    }
    __syncthreads();
    int kl2 = tid & 63;
    int cr = tid >> 6;
#pragma unroll
    for (int r = 0; r < 16; ++r) {
        int cl2 = cr * 16 + r;
        WT[(size_t)(c0 + cl2) * KTOT + k0 + kl2] = f2bf(tile[kl2][cl2]);
    }
}

// h0 = c0 = mean over 16 spatial positions of A[n,h,:,:]
__global__ __launch_bounds__(256) void init_state(const void* __restrict__ A,
                                                  const int* __restrict__ flagp,
                                                  float* __restrict__ h,
                                                  float* __restrict__ c) {
    int isbf = *flagp;
    int n = blockIdx.x;
    int tid = threadIdx.x;
#pragma unroll
    for (int j = 0; j < 2; ++j) {
        int hh = tid * 2 + j;
        size_t base = ((size_t)n * 512 + hh) * 16;
        float s = 0.f;
#pragma unroll
        for (int p = 0; p < 16; ++p) s += ldin(A, base + p, isbf);
        s *= (1.0f / 16.0f);
        h[n * 512 + hh] = s;
        c[n * 512 + hh] = s;
    }
}

// ---------------- grid barrier: relaxed spin, single acquire ----------------
#define GUARD_MAX (1 << 16)

__device__ __forceinline__ void gbar_arrive(unsigned* bar, int bid) {
    __syncthreads();   // all waves' stores issued + vmcnt drained
    if (threadIdx.x == 0)
        __hip_atomic_fetch_add(&bar[(bid & 7) << 5], 1u, __ATOMIC_RELEASE,
                               __HIP_MEMORY_SCOPE_AGENT);
}
__device__ __forceinline__ void gbar_wait(unsigned* bar, int bid, unsigned epoch) {
    if (threadIdx.x == 0) {
        if (bid == 0) {
#pragma unroll 1
            for (int g = 0; g < 8; ++g) {
                int guard = 0;
                while (__hip_atomic_load(&bar[g << 5], __ATOMIC_RELAXED,
                                         __HIP_MEMORY_SCOPE_AGENT) < epoch * 32u) {
                    __builtin_amdgcn_s_sleep(1);
                    if (++guard > GUARD_MAX) break;   // fail loud, not hung
                }
                (void)__hip_atomic_load(&bar[g << 5], __ATOMIC_ACQUIRE,
                                        __HIP_MEMORY_SCOPE_AGENT);
            }
            __hip_atomic_store(&bar[256], epoch, __ATOMIC_RELEASE,
                               __HIP_MEMORY_SCOPE_AGENT);
        } else {
            int guard = 0;
            while (__hip_atomic_load(&bar[256], __ATOMIC_RELAXED,
                                     __HIP_MEMORY_SCOPE_AGENT) < epoch) {
                __builtin_amdgcn_s_sleep(1);
                if (++guard > GUARD_MAX) break;
            }
            (void)__hip_atomic_load(&bar[256], __ATOMIC_ACQUIRE,
                                    __HIP_MEMORY_SCOPE_AGENT);
        }
    }
    __syncthreads();
}

// ---------------- staging helpers ----------------

__device__ __forceinline__ void gload_lds16(const void* g, void* l) {
    __builtin_amdgcn_global_load_lds(
        (const __attribute__((address_space(1))) void*)g,
        (__attribute__((address_space(3))) void*)l, 16, 0, 0);
}

// Stage one 64-row x 64-elem chunk (8 KB) into `slot`, LDS order
// [ksub2][mi4][lane16B] so frag reads are base + lane*16 (conflict-free).
// src (Acat layout, row stride 3072 B) already includes:
//   array base + n0*3072 + (lane&15)*3072 + (lane>>4)*16 + kbase*2.
__device__ __forceinline__ void stage8(const char* src, char* slot) {
#pragma unroll
    for (int j = 0; j < 8; ++j)
        gload_lds16(src + (size_t)((j & 3) * 49152 + (j >> 2) * 64),
                    slot + j * 1024);
}

// Same, but sourcing from x directly (bf16 input; row stride 64*512*2 B).
// src includes: x base + (n0+(lane&15))*65536 + t*1024 + (lane>>4)*16 + kbase*2.
__device__ __forceinline__ void stage8x(const char* src, char* slot) {
#pragma unroll
    for (int j = 0; j < 8; ++j)
        gload_lds16(src + (size_t)((j & 3) * 1048576 + (j >> 2) * 64),
                    slot + j * 1024);
}

// ---------------- the persistent fused kernel ----------------
// grid = 256 x 256 regular launch; ~131.5 KB LDS -> 1 block/CU -> co-resident.
// block: m-tile = bid&7 (64 batch rows; == XCD under round-robin dispatch,
// so all 32 blocks of an XCD share one m-tile -> L2 locality), cs = bid>>3.
// wave w: K-range [384w, 384w+384) for ALL 4 gates; B slice in 192 VGPRs.
__global__ __launch_bounds__(256, 1) void fused_all(
    const void* __restrict__ x, const void* __restrict__ A,
    const unsigned short* __restrict__ WT, const void* __restrict__ bias,
    const int* __restrict__ flagp, float* __restrict__ h, float* __restrict__ c,
    unsigned short* __restrict__ Ahi, unsigned short* __restrict__ Alo,
    unsigned* __restrict__ bar, void* __restrict__ out)
{
    const int isbf = *flagp;
    const int tid  = threadIdx.x;
    const int lane = tid & 63;
    const int wave = tid >> 6;
    const int bid  = blockIdx.x;
    const int n0   = (bid & 7) * 64;
    const int cs   = bid >> 3;

    __shared__ __align__(16) char ring[131072];   // 4 waves x 2 slots x (8K hi + 8K lo)
    __shared__ float wsum[4][16];

    // ---- one-time: B fragments (4 gates x 12 ksubs = 48 x bf16x8 = 192 VGPR)
    const int kw0 = wave * 384;
    bf16x8 Bb[48];
    {
#pragma unroll
        for (int ni = 0; ni < 4; ++ni) {
            const unsigned short* wp = WT
                + (size_t)(ni * 512 + cs * 16 + (lane & 15)) * KTOT
                + kw0 + (lane >> 4) * 8;
#pragma unroll
            for (int ks = 0; ks < 12; ++ks)
                Bb[ni * 12 + ks] = *(const bf16x8*)(wp + ks * 32);
        }
    }

    // ---- one-time: epilogue constants + c-state in registers ----
    const int ecol  = tid & 15;
    const int erow0 = (tid >> 4) * 4;
    const int hcol  = cs * 16 + ecol;
    const float bi  = ldin(bias, hcol,        isbf);
    const float bf_ = ldin(bias, 512 + hcol,  isbf);
    const float bo  = ldin(bias, 1024 + hcol, isbf);
    const float bg  = ldin(bias, 1536 + hcol, isbf);
    float cst[4];
#pragma unroll
    for (int j = 0; j < 4; ++j)
        cst[j] = c[(size_t)(n0 + erow0 + j) * 512 + hcol];

    // ---- one-time: prep constants + A cached in registers (bf16-packed) ----
    const int prow = tid >> 7;          // 0..1: which of the block's 2 rows
    const int ptl  = tid & 127;         // 128 threads per row
    const int pn   = bid * 2 + prow;    // batch row this half-block preps
    const int he0  = ptl * 4;           // 4 consecutive h per thread
    unsigned apk[4][8];                 // A[pn][he0+e][p] as packed bf16 pairs
    if (isbf) {
        const uint4* ap = (const uint4*)((const unsigned short*)A
                                         + ((size_t)pn * 512 + he0) * 16);
#pragma unroll
        for (int e = 0; e < 4; ++e) {
            uint4 a = ap[2 * e], b = ap[2 * e + 1];
            apk[e][0] = a.x; apk[e][1] = a.y; apk[e][2] = a.z; apk[e][3] = a.w;
            apk[e][4] = b.x; apk[e][5] = b.y; apk[e][6] = b.z; apk[e][7] = b.w;
        }
    } else {
        const float* ap = (const float*)A + ((size_t)pn * 512 + he0) * 16;
#pragma unroll
        for (int e = 0; e < 4; ++e)
#pragma unroll
            for (int q = 0; q < 8; ++q)
                apk[e][q] = (unsigned)f2bf(ap[e * 16 + 2 * q])
                          | ((unsigned)f2bf(ap[e * 16 + 2 * q + 1]) << 16);
    }

    // per-wave staging pointers (fixed)
    char* const slH[2] = { ring + wave * 32768,         ring + wave * 32768 + 8192 };
    char* const slL[2] = { ring + wave * 32768 + 16384, ring + wave * 32768 + 24576 };
    const size_t laneoff = (size_t)((lane & 15) * 3072 + (lane >> 4) * 16);
    const char* const srcH = (const char*)Ahi + (size_t)n0 * 3072 + laneoff;
    const char* const srcL = (const char*)Alo + (size_t)n0 * 3072 + laneoff;
    const char* const xrow = (const char*)x
        + (size_t)(n0 + (lane & 15)) * 65536 + (size_t)((lane >> 4) * 16);
    float* const accX = (float*)ring;   // [4][64][64] f32, reuses ring post-GEMM

#pragma unroll 1
    for (int t = 0; t < TS; ++t) {
        // ===================== P: attention + Acat build =====================
        {
            float4 hq = *(const float4*)&h[(size_t)pn * 512 + he0];
            float hv[4] = { hq.x, hq.y, hq.z, hq.w };
            float part[16];
#pragma unroll
            for (int p = 0; p < 16; ++p) part[p] = 0.f;
#pragma unroll
            for (int e = 0; e < 4; ++e)
#pragma unroll
                for (int q = 0; q < 8; ++q) {
                    unsigned u = apk[e][q];
                    union { unsigned u; float f; } lo, hi;
                    lo.u = u << 16; hi.u = u & 0xffff0000u;
                    part[2 * q]     += hv[e] * lo.f;
                    part[2 * q + 1] += hv[e] * hi.f;
                }
#pragma unroll
            for (int off = 32; off > 0; off >>= 1)
#pragma unroll
                for (int p = 0; p < 16; ++p) part[p] += __shfl_down(part[p], off, 64);
            if (lane == 0)
#pragma unroll
                for (int p = 0; p < 16; ++p) wsum[wave][p] = part[p];
            __syncthreads();

            const float scale = 0.04419417382415922f;  // 1/sqrt(512)
            float sc[16], mx = -1e30f;
#pragma unroll
            for (int p = 0; p < 16; ++p) {
                sc[p] = (wsum[prow * 2][p] + wsum[prow * 2 + 1][p]) * scale;
                mx = fmaxf(mx, sc[p]);
            }
            float ssum = 0.f;
#pragma unroll
            for (int p = 0; p < 16; ++p) { sc[p] = __expf(sc[p] - mx); ssum += sc[p]; }
            const float inv = 1.0f / ssum;

            float at[4];
#pragma unroll
            for (int e = 0; e < 4; ++e) {
                float s = 0.f;
#pragma unroll
                for (int q = 0; q < 8; ++q) {
                    unsigned u = apk[e][q];
                    union { unsigned u; float f; } lo, hi;
                    lo.u = u << 16; hi.u = u & 0xffff0000u;
                    s += lo.f * sc[2 * q] + hi.f * sc[2 * q + 1];
                }
                at[e] = s * inv;
            }

            unsigned short* hrow = Ahi + (size_t)pn * KTOT;
            unsigned short* lrow = Alo + (size_t)pn * KTOT;
            // x region (k 0..511): only needed in Acat for fp32 inputs
            // (bf16 path stages x chunks directly from x).
            if (!isbf) {
                const float* xp = (const float*)x + ((size_t)pn * TS + t) * 512 + he0;
                ushort4 v = { f2bf(xp[0]), f2bf(xp[1]), f2bf(xp[2]), f2bf(xp[3]) };
                *(ushort4*)&hrow[he0] = v;
            }
            // h region (k 512..1023) hi+lo
            {
                ushort4 hiv, lov;
#pragma unroll
                for (int e = 0; e < 4; ++e) {
                    unsigned short hb = f2bf(hv[e]);
                    hiv[e] = hb; lov[e] = f2bf(hv[e] - bf2f(hb));
                }
                *(ushort4*)&hrow[512 + he0] = hiv;
                *(ushort4*)&lrow[512 + he0] = lov;
            }
            // attn region (k 1024..1535) hi+lo
            {
                ushort4 hiv, lov;
#pragma unroll
                for (int e = 0; e < 4; ++e) {
                    unsigned short hb = f2bf(at[e]);
                    hiv[e] = hb; lov[e] = f2bf(at[e] - bf2f(hb));
                }
                *(ushort4*)&hrow[1024 + he0] = hiv;
                *(ushort4*)&lrow[1024 + he0] = lov;
            }
        }

        gbar_arrive(bar, bid);
        // x-direct prologue chunks are step-independent: issue under the spin
        const char* xsrc = xrow + (size_t)t * 1024;
        if (isbf) {
            if (kw0 < 512)      stage8x(xsrc + (size_t)kw0 * 2, slH[0]);
            if (kw0 + 64 < 512) stage8x(xsrc + (size_t)(kw0 + 64) * 2, slH[1]);
        }
        gbar_wait(bar, bid, 2u * t + 1u);
        // remaining prologue chunks (Acat-sourced)
        if (!(isbf && kw0 < 512)) {
            stage8(srcH + (size_t)kw0 * 2, slH[0]);
            if (kw0 >= 512) stage8(srcL + (size_t)kw0 * 2, slL[0]);
        }
        if (!(isbf && kw0 + 64 < 512)) {
            const int kb1 = kw0 + 64;
            stage8(srcH + (size_t)kb1 * 2, slH[1]);
            if (kb1 >= 512) stage8(srcL + (size_t)kb1 * 2, slL[1]);
        }

        // ===================== G: K-split GEMM, per-wave pipeline =====================
        f32x4 acc[4][4];   // [mi][ni]
#pragma unroll
        for (int mi = 0; mi < 4; ++mi)
#pragma unroll
            for (int ni = 0; ni < 4; ++ni) acc[mi][ni] = (f32x4){0.f, 0.f, 0.f, 0.f};

#pragma unroll
        for (int i = 0; i < 6; ++i) {
            // wave-exact counted wait: chunk i retired <=> vmcnt(ops(chunk i+1))
            if (i < 5) {
                if (kw0 + (i + 1) * 64 < 512)
                    asm volatile("s_waitcnt vmcnt(8)" ::: "memory");
                else
                    asm volatile("s_waitcnt vmcnt(16)" ::: "memory");
            } else {
                asm volatile("s_waitcnt vmcnt(0)" ::: "memory");
            }
            __builtin_amdgcn_sched_barrier(0);
            const int kbase = kw0 + i * 64;
            const bool xc = (kbase < 512);     // wave-uniform
            char* sH = slH[i & 1];
            char* sL = slL[i & 1];
            bf16x8 ah0[4], ah1[4], al0[4], al1[4];
#pragma unroll
            for (int mi = 0; mi < 4; ++mi) {
                ah0[mi] = *(const bf16x8*)(sH + mi * 1024 + lane * 16);
                ah1[mi] = *(const bf16x8*)(sH + 4096 + mi * 1024 + lane * 16);
            }
            if (!xc) {
#pragma unroll
                for (int mi = 0; mi < 4; ++mi) {
                    al0[mi] = *(const bf16x8*)(sL + mi * 1024 + lane * 16);
                    al1[mi] = *(const bf16x8*)(sL + 4096 + mi * 1024 + lane * 16);
                }
            }
            // all ds_reads of this slot done before its DMA overwrite issues
            asm volatile("s_waitcnt lgkmcnt(0)" ::: "memory");
            __builtin_amdgcn_sched_barrier(0);
            if (i < 4) {
                const int nkb = kw0 + (i + 2) * 64;
                if (isbf && nkb < 512) {
                    stage8x(xsrc + (size_t)nkb * 2, slH[i & 1]);
                } else {
                    stage8(srcH + (size_t)nkb * 2, slH[i & 1]);
                    if (nkb >= 512) stage8(srcL + (size_t)nkb * 2, slL[i & 1]);
                }
            }
            __builtin_amdgcn_sched_barrier(0);
#pragma unroll
            for (int ni = 0; ni < 4; ++ni)
#pragma unroll
                for (int mi = 0; mi < 4; ++mi)
                    acc[mi][ni] = __builtin_amdgcn_mfma_f32_16x16x32_bf16(
                        ah0[mi], Bb[ni * 12 + i * 2], acc[mi][ni], 0, 0, 0);
#pragma unroll
            for (int ni = 0; ni < 4; ++ni)
#pragma unroll
                for (int mi = 0; mi < 4; ++mi)
                    acc[mi][ni] = __builtin_amdgcn_mfma_f32_16x16x32_bf16(
                        ah1[mi], Bb[ni * 12 + i * 2 + 1], acc[mi][ni], 0, 0, 0);
            if (!xc) {
#pragma unroll
                for (int ni = 0; ni < 4; ++ni)
#pragma unroll
                    for (int mi = 0; mi < 4; ++mi)
                        acc[mi][ni] = __builtin_amdgcn_mfma_f32_16x16x32_bf16(
                            al0[mi], Bb[ni * 12 + i * 2], acc[mi][ni], 0, 0, 0);
#pragma unroll
                for (int ni = 0; ni < 4; ++ni)
#pragma unroll
                    for (int mi = 0; mi < 4; ++mi)
                        acc[mi][ni] = __builtin_amdgcn_mfma_f32_16x16x32_bf16(
                            al1[mi], Bb[ni * 12 + i * 2 + 1], acc[mi][ni], 0, 0, 0);
            }
        }

        // ---- cross-wave K-reduce through LDS (ring reused as accX) ----
        __syncthreads();
#pragma unroll
        for (int mi = 0; mi < 4; ++mi)
#pragma unroll
            for (int ni = 0; ni < 4; ++ni)
#pragma unroll
                for (int r = 0; r < 4; ++r)
                    accX[wave * 4096
                         + (mi * 16 + (lane >> 4) * 4 + r) * 64
                         + ni * 16 + (lane & 15)] = acc[mi][ni][r];
        __syncthreads();

        // ---- fused LSTM epilogue ----
#pragma unroll
        for (int j = 0; j < 4; ++j) {
            const int r = erow0 + j;
            const int n = n0 + r;
            float s[4];
#pragma unroll
            for (int g = 0; g < 4; ++g) {
                const int base = r * 64 + g * 16 + ecol;
                s[g] = accX[base] + accX[4096 + base]
                     + accX[8192 + base] + accX[12288 + base];
            }
            const float xi = s[0] + bi;
            const float xf = s[1] + bf_;
            const float xo = s[2] + bo;
            const float xg = s[3] + bg;
            const float iv = 1.f / (1.f + __expf(-xi));
            const float fv = 1.f / (1.f + __expf(-xf));
            const float ov = 1.f / (1.f + __expf(-xo));
            const float gv = 1.f - 2.f / (__expf(2.f * xg) + 1.f);     // tanh
            const float cnew = fv * cst[j] + iv * gv;
            const float tc = 1.f - 2.f / (__expf(2.f * cnew) + 1.f);   // tanh
            const float hnew = ov * tc;
            cst[j] = cnew;
            h[(size_t)n * 512 + hcol] = hnew;
            const size_t oidx = ((size_t)n * TS + t) * 512 + hcol;
            if (isbf) ((__hip_bfloat16*)out)[oidx] = __float2bfloat16(hnew);
            else      ((float*)out)[oidx] = hnew;
        }

        if (t != TS - 1) {
            gbar_arrive(bar, bid);
            gbar_wait(bar, bid, 2u * t + 2u);
        }
    }
}

// ---------------- launch ----------------

extern "C" void kernel_launch(void* const* d_in, const int* in_sizes, int n_in,
                              void* d_out, int out_size, void* d_ws, size_t ws_size,
                              hipStream_t stream) {
    const void* x     = d_in[0];
    const void* A     = d_in[1];
    const void* Wx    = d_in[2];
    const void* Wh    = d_in[3];
    const void* Wattn = d_in[4];
    const void* bias  = d_in[5];

    char* ws = (char*)d_ws;
    const size_t WSZ = (size_t)2048 * KTOT * 2;   // 6291456 B
    const size_t ASZ = (size_t)NBATCH * KTOT * 2; // 1572864 B
    unsigned short* WT  = (unsigned short*)ws;
    unsigned short* Ahi = (unsigned short*)(ws + WSZ);
    unsigned short* Alo = (unsigned short*)(ws + WSZ + ASZ);
    float* hbuf = (float*)(ws + WSZ + 2 * ASZ);
    float* cbuf = (float*)(ws + WSZ + 2 * ASZ + 1048576);
    char*  misc = ws + WSZ + 2 * ASZ + 2 * 1048576;
    int* flag     = (int*)misc;
    unsigned* bar = (unsigned*)(misc + 1024);     // 257 u32, zeroed below

    hipMemsetAsync(misc, 0, 4096, stream);
    detect_dtype<<<1, 256, 0, stream>>>(x, flag);
    build_wT<<<dim3(24, 32), 256, 0, stream>>>(Wx, Wh, Wattn, flag, WT);
    init_state<<<512, 256, 0, stream>>>(A, flag, hbuf, cbuf);
    fused_all<<<256, 256, 0, stream>>>(x, A, WT, bias, flag, hbuf, cbuf,
                                       Ahi, Alo, bar, d_out);
}

// Round 7
// 2019.498 us; speedup vs baseline: 2.6609x; 1.9690x over previous
//
#include <hip/hip_runtime.h>
#include <hip/hip_bf16.h>

// N=512, T=64, D=512, H=512, 4H=2048, K = D+2H = 1536
// Round 11: back to multi-launch (2 kernels/step), keeping every proven-fast
// component of the round-4 persistent kernel and dropping the broken one:
//  - cross-block sync = kernel launch boundaries (runtime-guaranteed
//    visibility; proven in this harness by round 0's 130-dispatch version;
//    graph capture keeps per-launch gap ~1 us). No atomics, no spin barriers.
//  - gemm_step: round-4 verbatim K-split-per-wave GEMM (wave w owns k in
//    [384w,384w+384) for all 4 gates), per-wave double-buffered
//    global_load_lds staging with wave-exact counted vmcnt, x-region staged
//    directly from x (bf16), conflict-free LDS layout, fused LSTM epilogue.
//  - B reloaded per launch from a fragment-contiguous layout WB (built once)
//    -> 48 coalesced dwordx4 per thread; one vmcnt(0) drains B before the
//    staging prologue so the K-loop's counted-vmcnt arithmetic is unchanged.
//  - c-state round-trips global per launch (4 KB/block).
// Rounds 5/6 (persistent + XCD-local barrier) failed with subtle wrongness;
// round 4 (persistent + agent barriers) passed but L2-invalidated itself to
// 62 us/step. This design needs neither.
#define NBATCH 512
#define TS   64
#define KTOT 1536

typedef short bf16x8 __attribute__((ext_vector_type(8)));
typedef float f32x4  __attribute__((ext_vector_type(4)));

__device__ __forceinline__ unsigned short f2bf(float v) {
    union { float f; unsigned u; } c; c.f = v;
    unsigned r = (c.u + 0x7fffu + ((c.u >> 16) & 1u)) >> 16;  // RTNE
    return (unsigned short)r;
}
__device__ __forceinline__ float bf2f(unsigned short b) {
    union { unsigned u; float f; } c; c.u = (unsigned)b << 16; return c.f;
}
__device__ __forceinline__ float ldin(const void* p, size_t i, int isbf) {
    if (isbf) return bf2f(((const unsigned short*)p)[i]);
    return ((const float*)p)[i];
}

// Detect input dtype: sample even-index ushorts of x, decode as bf16.
__global__ void detect_dtype(const void* x, int* flag) {
    __shared__ int bad;
    if (threadIdx.x == 0) bad = 0;
    __syncthreads();
    const unsigned short* u = (const unsigned short*)x;
    int mybad = 0;
    for (int k = 0; k < 16; ++k) {
        size_t i = (size_t)(threadIdx.x + k * 256) * 1987 + 3;
        float v = bf2f(u[2 * i]);
        if (!(fabsf(v) < 1000.0f)) mybad = 1;
    }
    if (mybad) atomicOr(&bad, 1);
    __syncthreads();
    if (threadIdx.x == 0) *flag = (bad == 0) ? 1 : 0;
}

// ---------------- one-time setup ----------------

// WB: fragment-contiguous bf16 weights.
// Element (cs, w, ni, ks, lane, e) = W^T[col][k],
//   col = ni*512 + cs*16 + (lane&15),  k = w*384 + ks*32 + (lane>>4)*8 + e
// at flat index ((cs*4 + w)*48 + ni*12 + ks)*512 + lane*8 + e.
// k<512 -> Wx, <1024 -> Wh, else Wattn (row-major [k][2048]).
__global__ __launch_bounds__(256) void build_wB(const void* __restrict__ Wx,
                                                const void* __restrict__ Wh,
                                                const void* __restrict__ Wattn,
                                                const int* __restrict__ flagp,
                                                unsigned short* __restrict__ WB) {
    int isbf = *flagp;
    int cs = blockIdx.x;          // 0..31
    int w  = blockIdx.y;          // 0..3
    int tid = threadIdx.x;
    int ni = tid >> 6;            // 0..3 (gate)
    int l  = tid & 63;
    int col = ni * 512 + cs * 16 + (l & 15);
    int kr  = (l >> 4) * 8;
    unsigned short* dst = WB
        + (size_t)((cs * 4 + w) * 48 + ni * 12) * 512 + l * 8;
#pragma unroll 1
    for (int ks = 0; ks < 12; ++ks) {
        int k0 = w * 384 + ks * 32 + kr;   // multiple of 8; 8-group stays in one region
        unsigned short v[8];
#pragma unroll
        for (int e = 0; e < 8; ++e) {
            int k = k0 + e;
            const void* s; size_t off;
            if (k < 512)       { s = Wx;    off = (size_t)k * 2048 + col; }
            else if (k < 1024) { s = Wh;    off = (size_t)(k - 512) * 2048 + col; }
            else               { s = Wattn; off = (size_t)(k - 1024) * 2048 + col; }
            v[e] = f2bf(ldin(s, off, isbf));
        }
        *(ushort4*)(dst + (size_t)ks * 512)     = *(ushort4*)&v[0];
        *(ushort4*)(dst + (size_t)ks * 512 + 4) = *(ushort4*)&v[4];
    }
}

// h0 = c0 = mean over 16 spatial positions of A[n,h,:,:]
__global__ __launch_bounds__(256) void init_state(const void* __restrict__ A,
                                                  const int* __restrict__ flagp,
                                                  float* __restrict__ h,
                                                  float* __restrict__ c) {
    int isbf = *flagp;
    int n = blockIdx.x;
    int tid = threadIdx.x;
#pragma unroll
    for (int j = 0; j < 2; ++j) {
        int hh = tid * 2 + j;
        size_t base = ((size_t)n * 512 + hh) * 16;
        float s = 0.f;
#pragma unroll
        for (int p = 0; p < 16; ++p) s += ldin(A, base + p, isbf);
        s *= (1.0f / 16.0f);
        h[n * 512 + hh] = s;
        c[n * 512 + hh] = s;
    }
}

// ---------------- per-step kernel 1: prep (attention + Acat) ----------------
// 256 blocks x 256 threads; block b preps rows 2b, 2b+1 (128 threads/row).
__global__ __launch_bounds__(256) void prep_step(const void* __restrict__ x,
                                                 const void* __restrict__ A,
                                                 const int* __restrict__ flagp,
                                                 const float* __restrict__ h,
                                                 unsigned short* __restrict__ Ahi,
                                                 unsigned short* __restrict__ Alo,
                                                 int t) {
    const int isbf = *flagp;
    const int tid  = threadIdx.x;
    const int lane = tid & 63;
    const int wave = tid >> 6;
    const int bid  = blockIdx.x;
    __shared__ float wsum[4][16];

    const int prow = tid >> 7;          // 0..1
    const int ptl  = tid & 127;         // 128 threads per row
    const int pn   = bid * 2 + prow;
    const int he0  = ptl * 4;           // 4 consecutive h per thread

    // A[pn][he0+e][p] as packed bf16 pairs (8 u32 per e)
    unsigned apk[4][8];
    if (isbf) {
        const uint4* ap = (const uint4*)((const unsigned short*)A
                                         + ((size_t)pn * 512 + he0) * 16);
#pragma unroll
        for (int e = 0; e < 4; ++e) {
            uint4 a = ap[2 * e], b = ap[2 * e + 1];
            apk[e][0] = a.x; apk[e][1] = a.y; apk[e][2] = a.z; apk[e][3] = a.w;
            apk[e][4] = b.x; apk[e][5] = b.y; apk[e][6] = b.z; apk[e][7] = b.w;
        }
    } else {
        const float* ap = (const float*)A + ((size_t)pn * 512 + he0) * 16;
#pragma unroll
        for (int e = 0; e < 4; ++e)
#pragma unroll
            for (int q = 0; q < 8; ++q)
                apk[e][q] = (unsigned)f2bf(ap[e * 16 + 2 * q])
                          | ((unsigned)f2bf(ap[e * 16 + 2 * q + 1]) << 16);
    }

    float4 hq = *(const float4*)&h[(size_t)pn * 512 + he0];
    float hv[4] = { hq.x, hq.y, hq.z, hq.w };

    float part[16];
#pragma unroll
    for (int p = 0; p < 16; ++p) part[p] = 0.f;
#pragma unroll
    for (int e = 0; e < 4; ++e)
#pragma unroll
        for (int q = 0; q < 8; ++q) {
            unsigned u = apk[e][q];
            union { unsigned u; float f; } lo, hi;
            lo.u = u << 16; hi.u = u & 0xffff0000u;
            part[2 * q]     += hv[e] * lo.f;
            part[2 * q + 1] += hv[e] * hi.f;
        }
#pragma unroll
    for (int off = 32; off > 0; off >>= 1)
#pragma unroll
        for (int p = 0; p < 16; ++p) part[p] += __shfl_down(part[p], off, 64);
    if (lane == 0)
#pragma unroll
        for (int p = 0; p < 16; ++p) wsum[wave][p] = part[p];
    __syncthreads();

    const float scale = 0.04419417382415922f;  // 1/sqrt(512)
    float sc[16], mx = -1e30f;
#pragma unroll
    for (int p = 0; p < 16; ++p) {
        sc[p] = (wsum[prow * 2][p] + wsum[prow * 2 + 1][p]) * scale;
        mx = fmaxf(mx, sc[p]);
    }
    float ssum = 0.f;
#pragma unroll
    for (int p = 0; p < 16; ++p) { sc[p] = __expf(sc[p] - mx); ssum += sc[p]; }
    const float inv = 1.0f / ssum;

    float at[4];
#pragma unroll
    for (int e = 0; e < 4; ++e) {
        float s = 0.f;
#pragma unroll
        for (int q = 0; q < 8; ++q) {
            unsigned u = apk[e][q];
            union { unsigned u; float f; } lo, hi;
            lo.u = u << 16; hi.u = u & 0xffff0000u;
            s += lo.f * sc[2 * q] + hi.f * sc[2 * q + 1];
        }
        at[e] = s * inv;
    }

    unsigned short* hrow = Ahi + (size_t)pn * KTOT;
    unsigned short* lrow = Alo + (size_t)pn * KTOT;
    // x region (k 0..511): only needed in Acat for fp32 inputs
    // (bf16 path stages x chunks directly from x in gemm_step).
    if (!isbf) {
        const float* xp = (const float*)x + ((size_t)pn * TS + t) * 512 + he0;
        ushort4 v = { f2bf(xp[0]), f2bf(xp[1]), f2bf(xp[2]), f2bf(xp[3]) };
        *(ushort4*)&hrow[he0] = v;
    }
    // h region (k 512..1023) hi+lo
    {
        ushort4 hiv, lov;
#pragma unroll
        for (int e = 0; e < 4; ++e) {
            unsigned short hb = f2bf(hv[e]);
            hiv[e] = hb; lov[e] = f2bf(hv[e] - bf2f(hb));
        }
        *(ushort4*)&hrow[512 + he0] = hiv;
        *(ushort4*)&lrow[512 + he0] = lov;
    }
    // attn region (k 1024..1535) hi+lo
    {
        ushort4 hiv, lov;
#pragma unroll
        for (int e = 0; e < 4; ++e) {
            unsigned short hb = f2bf(at[e]);
            hiv[e] = hb; lov[e] = f2bf(at[e] - bf2f(hb));
        }
        *(ushort4*)&hrow[1024 + he0] = hiv;
        *(ushort4*)&lrow[1024 + he0] = lov;
    }
}

// ---------------- staging helpers ----------------

__device__ __forceinline__ void gload_lds16(const void* g, void* l) {
    __builtin_amdgcn_global_load_lds(
        (const __attribute__((address_space(1))) void*)g,
        (__attribute__((address_space(3))) void*)l, 16, 0, 0);
}

// Stage one 64-row x 64-elem chunk (8 KB) into `slot`, LDS order
// [ksub2][mi4][lane16B] so frag reads are base + lane*16 (conflict-free).
// src (Acat layout, row stride 3072 B) already includes:
//   array base + n0*3072 + (lane&15)*3072 + (lane>>4)*16 + kbase*2.
__device__ __forceinline__ void stage8(const char* src, char* slot) {
#pragma unroll
    for (int j = 0; j < 8; ++j)
        gload_lds16(src + (size_t)((j & 3) * 49152 + (j >> 2) * 64),
                    slot + j * 1024);
}

// Same, sourcing from x directly (bf16 input; row stride 64*512*2 B).
// src includes: x base + (n0+(lane&15))*65536 + t*1024 + (lane>>4)*16 + kbase*2.
__device__ __forceinline__ void stage8x(const char* src, char* slot) {
#pragma unroll
    for (int j = 0; j < 8; ++j)
        gload_lds16(src + (size_t)((j & 3) * 1048576 + (j >> 2) * 64),
                    slot + j * 1024);
}

// ---------------- per-step kernel 2: GEMM + LSTM epilogue ----------------
// 256 blocks x 256 threads, ~128 KB LDS -> 1 block/CU.
// block: m = bid&7 (64 batch rows), cs = bid>>3 (16 h-cols).
// wave w: K-range [384w, 384w+384) for ALL 4 gates; B slice in 192 VGPRs
// reloaded per launch from WB (coalesced).
__global__ __launch_bounds__(256, 1) void gemm_step(
    const void* __restrict__ x, const unsigned short* __restrict__ WB,
    const void* __restrict__ bias, const int* __restrict__ flagp,
    float* __restrict__ h, float* __restrict__ c,
    const unsigned short* __restrict__ Ahi, const unsigned short* __restrict__ Alo,
    void* __restrict__ out, int t)
{
    const int isbf = *flagp;
    const int tid  = threadIdx.x;
    const int lane = tid & 63;
    const int wave = tid >> 6;
    const int bid  = blockIdx.x;
    const int m    = bid & 7;
    const int cs   = bid >> 3;
    const int n0   = m * 64;

    __shared__ __align__(16) char ring[131072];   // 4 waves x 2 slots x (8K hi + 8K lo)

    // ---- epilogue constants + c slab (per launch) ----
    const int ecol  = tid & 15;
    const int erow0 = (tid >> 4) * 4;
    const int hcol  = cs * 16 + ecol;
    const float bi  = ldin(bias, hcol,        isbf);
    const float bf_ = ldin(bias, 512 + hcol,  isbf);
    const float bo  = ldin(bias, 1024 + hcol, isbf);
    const float bg  = ldin(bias, 1536 + hcol, isbf);
    float cst[4];
#pragma unroll
    for (int j = 0; j < 4; ++j)
        cst[j] = c[(size_t)(n0 + erow0 + j) * 512 + hcol];

    // ---- B fragments (48 x bf16x8 = 192 VGPR), coalesced from WB ----
    const int kw0 = wave * 384;
    bf16x8 Bb[48];
    {
        const unsigned short* wb = WB
            + (size_t)((cs * 4 + wave) * 48) * 512 + lane * 8;
#pragma unroll
        for (int f = 0; f < 48; ++f)
            Bb[f] = *(const bf16x8*)(wb + (size_t)f * 512);
    }
    // drain B (and bias/c) so the staging pipeline's vmcnt counts are exact
    asm volatile("s_waitcnt vmcnt(0)" ::: "memory");

    // per-wave staging pointers
    char* const slH[2] = { ring + wave * 32768,         ring + wave * 32768 + 8192 };
    char* const slL[2] = { ring + wave * 32768 + 16384, ring + wave * 32768 + 24576 };
    const size_t laneoff = (size_t)((lane & 15) * 3072 + (lane >> 4) * 16);
    const char* const srcH = (const char*)Ahi + (size_t)n0 * 3072 + laneoff;
    const char* const srcL = (const char*)Alo + (size_t)n0 * 3072 + laneoff;
    const char* const xrow = (const char*)x
        + (size_t)(n0 + (lane & 15)) * 65536 + (size_t)((lane >> 4) * 16);
    const char* const xsrc = xrow + (size_t)t * 1024;
    float* const accX = (float*)ring;   // [4][64][64] f32, reuses ring post-GEMM

    // ---- prologue staging: chunks 0,1 of this wave's K-range ----
    if (isbf && kw0 < 512) stage8x(xsrc + (size_t)kw0 * 2, slH[0]);
    else {
        stage8(srcH + (size_t)kw0 * 2, slH[0]);
        if (kw0 >= 512) stage8(srcL + (size_t)kw0 * 2, slL[0]);
    }
    {
        const int kb1 = kw0 + 64;
        if (isbf && kb1 < 512) stage8x(xsrc + (size_t)kb1 * 2, slH[1]);
        else {
            stage8(srcH + (size_t)kb1 * 2, slH[1]);
            if (kb1 >= 512) stage8(srcL + (size_t)kb1 * 2, slL[1]);
        }
    }

    // ---- K-split GEMM, per-wave double-buffered pipeline ----
    f32x4 acc[4][4];   // [mi][ni]
#pragma unroll
    for (int mi = 0; mi < 4; ++mi)
#pragma unroll
        for (int ni = 0; ni < 4; ++ni) acc[mi][ni] = (f32x4){0.f, 0.f, 0.f, 0.f};

#pragma unroll
    for (int i = 0; i < 6; ++i) {
        // wave-exact counted wait: chunk i retired <=> vmcnt(ops(chunk i+1))
        if (i < 5) {
            if (kw0 + (i + 1) * 64 < 512)
                asm volatile("s_waitcnt vmcnt(8)" ::: "memory");
            else
                asm volatile("s_waitcnt vmcnt(16)" ::: "memory");
        } else {
            asm volatile("s_waitcnt vmcnt(0)" ::: "memory");
        }
        __builtin_amdgcn_sched_barrier(0);
        const int kbase = kw0 + i * 64;
        const bool xc = (kbase < 512);     // wave-uniform
        char* sH = slH[i & 1];
        char* sL = slL[i & 1];
        bf16x8 ah0[4], ah1[4], al0[4], al1[4];
#pragma unroll
        for (int mi = 0; mi < 4; ++mi) {
            ah0[mi] = *(const bf16x8*)(sH + mi * 1024 + lane * 16);
            ah1[mi] = *(const bf16x8*)(sH + 4096 + mi * 1024 + lane * 16);
        }
        if (!xc) {
#pragma unroll
            for (int mi = 0; mi < 4; ++mi) {
                al0[mi] = *(const bf16x8*)(sL + mi * 1024 + lane * 16);
                al1[mi] = *(const bf16x8*)(sL + 4096 + mi * 1024 + lane * 16);
            }
        }
        // all ds_reads of this slot done before its DMA overwrite issues
        asm volatile("s_waitcnt lgkmcnt(0)" ::: "memory");
        __builtin_amdgcn_sched_barrier(0);
        if (i < 4) {
            const int nkb = kw0 + (i + 2) * 64;
            if (isbf && nkb < 512) {
                stage8x(xsrc + (size_t)nkb * 2, slH[i & 1]);
            } else {
                stage8(srcH + (size_t)nkb * 2, slH[i & 1]);
                if (nkb >= 512) stage8(srcL + (size_t)nkb * 2, slL[i & 1]);
            }
        }
        __builtin_amdgcn_sched_barrier(0);
#pragma unroll
        for (int ni = 0; ni < 4; ++ni)
#pragma unroll
            for (int mi = 0; mi < 4; ++mi)
                acc[mi][ni] = __builtin_amdgcn_mfma_f32_16x16x32_bf16(
                    ah0[mi], Bb[ni * 12 + i * 2], acc[mi][ni], 0, 0, 0);
#pragma unroll
        for (int ni = 0; ni < 4; ++ni)
#pragma unroll
            for (int mi = 0; mi < 4; ++mi)
                acc[mi][ni] = __builtin_amdgcn_mfma_f32_16x16x32_bf16(
                    ah1[mi], Bb[ni * 12 + i * 2 + 1], acc[mi][ni], 0, 0, 0);
        if (!xc) {
#pragma unroll
            for (int ni = 0; ni < 4; ++ni)
#pragma unroll
                for (int mi = 0; mi < 4; ++mi)
                    acc[mi][ni] = __builtin_amdgcn_mfma_f32_16x16x32_bf16(
                        al0[mi], Bb[ni * 12 + i * 2], acc[mi][ni], 0, 0, 0);
#pragma unroll
            for (int ni = 0; ni < 4; ++ni)
#pragma unroll
                for (int mi = 0; mi < 4; ++mi)
                    acc[mi][ni] = __builtin_amdgcn_mfma_f32_16x16x32_bf16(
                        al1[mi], Bb[ni * 12 + i * 2 + 1], acc[mi][ni], 0, 0, 0);
        }
    }

    // ---- cross-wave K-reduce through LDS (ring reused as accX) ----
    __syncthreads();
#pragma unroll
    for (int mi = 0; mi < 4; ++mi)
#pragma unroll
        for (int ni = 0; ni < 4; ++ni)
#pragma unroll
            for (int r = 0; r < 4; ++r)
                accX[wave * 4096
                     + (mi * 16 + (lane >> 4) * 4 + r) * 64
                     + ni * 16 + (lane & 15)] = acc[mi][ni][r];
    __syncthreads();

    // ---- fused LSTM epilogue ----
#pragma unroll
    for (int j = 0; j < 4; ++j) {
        const int r = erow0 + j;
        const int n = n0 + r;
        float s[4];
#pragma unroll
        for (int g = 0; g < 4; ++g) {
            const int base = r * 64 + g * 16 + ecol;
            s[g] = accX[base] + accX[4096 + base]
                 + accX[8192 + base] + accX[12288 + base];
        }
        const float xi = s[0] + bi;
        const float xf = s[1] + bf_;
        const float xo = s[2] + bo;
        const float xg = s[3] + bg;
        const float iv = 1.f / (1.f + __expf(-xi));
        const float fv = 1.f / (1.f + __expf(-xf));
        const float ov = 1.f / (1.f + __expf(-xo));
        const float gv = 1.f - 2.f / (__expf(2.f * xg) + 1.f);     // tanh
        const float cnew = fv * cst[j] + iv * gv;
        const float tc = 1.f - 2.f / (__expf(2.f * cnew) + 1.f);   // tanh
        const float hnew = ov * tc;
        c[(size_t)n * 512 + hcol] = cnew;
        h[(size_t)n * 512 + hcol] = hnew;
        const size_t oidx = ((size_t)n * TS + t) * 512 + hcol;
        if (isbf) ((__hip_bfloat16*)out)[oidx] = __float2bfloat16(hnew);
        else      ((float*)out)[oidx] = hnew;
    }
}

// ---------------- launch ----------------

extern "C" void kernel_launch(void* const* d_in, const int* in_sizes, int n_in,
                              void* d_out, int out_size, void* d_ws, size_t ws_size,
                              hipStream_t stream) {
    const void* x     = d_in[0];
    const void* A     = d_in[1];
    const void* Wx    = d_in[2];
    const void* Wh    = d_in[3];
    const void* Wattn = d_in[4];
    const void* bias  = d_in[5];

    char* ws = (char*)d_ws;
    const size_t WSZ = (size_t)2048 * KTOT * 2;   // 6291456 B
    const size_t ASZ = (size_t)NBATCH * KTOT * 2; // 1572864 B
    unsigned short* WB  = (unsigned short*)ws;
    unsigned short* Ahi = (unsigned short*)(ws + WSZ);
    unsigned short* Alo = (unsigned short*)(ws + WSZ + ASZ);
    float* hbuf = (float*)(ws + WSZ + 2 * ASZ);
    float* cbuf = (float*)(ws + WSZ + 2 * ASZ + 1048576);
    int* flag   = (int*)(ws + WSZ + 2 * ASZ + 2 * 1048576);

    detect_dtype<<<1, 256, 0, stream>>>(x, flag);
    build_wB<<<dim3(32, 4), 256, 0, stream>>>(Wx, Wh, Wattn, flag, WB);
    init_state<<<512, 256, 0, stream>>>(A, flag, hbuf, cbuf);
    for (int t = 0; t < TS; ++t) {
        prep_step<<<256, 256, 0, stream>>>(x, A, flag, hbuf, Ahi, Alo, t);
        gemm_step<<<256, 256, 0, stream>>>(x, WB, bias, flag, hbuf, cbuf,
                                           Ahi, Alo, d_out, t);
    }
}

// Round 8
// 1734.025 us; speedup vs baseline: 3.0990x; 1.1646x over previous
//
#include <hip/hip_runtime.h>
#include <hip/hip_bf16.h>

// N=512, T=64, D=512, H=512, 4H=2048, K = D+2H = 1536
// Round 12: round-11 structure (2 launches/step, launch-boundary sync,
// K-split-per-wave GEMM with register-resident B reloaded per launch) plus:
//  - XCD-rectangle mapping: with round-robin bid->XCD (bid%8), pick
//    m=(g>>2)*4+(j>>3), cs=(g&3)*8+(j&7) so each XCD hosts 4 m-tiles x
//    8 cs-slices. B slices shared 8-way now hit the XCD's own L2 (LLC
//    inflow ~53 -> ~25 MB/step despite the per-launch L2 invalidate).
//  - B-load drain (vmcnt(0)) removed; sched_barrier(0) keeps B-loads
//    ordered before staging DMAs so the wave-exact counted vmcnt still
//    implies B completion (B ops are older than stage0). B fetch now
//    overlaps the staging prologue instead of serializing before it.
#define NBATCH 512
#define TS   64
#define KTOT 1536

typedef short bf16x8 __attribute__((ext_vector_type(8)));
typedef float f32x4  __attribute__((ext_vector_type(4)));

__device__ __forceinline__ unsigned short f2bf(float v) {
    union { float f; unsigned u; } c; c.f = v;
    unsigned r = (c.u + 0x7fffu + ((c.u >> 16) & 1u)) >> 16;  // RTNE
    return (unsigned short)r;
}
__device__ __forceinline__ float bf2f(unsigned short b) {
    union { unsigned u; float f; } c; c.u = (unsigned)b << 16; return c.f;
}
__device__ __forceinline__ float ldin(const void* p, size_t i, int isbf) {
    if (isbf) return bf2f(((const unsigned short*)p)[i]);
    return ((const float*)p)[i];
}

// Detect input dtype: sample even-index ushorts of x, decode as bf16.
__global__ void detect_dtype(const void* x, int* flag) {
    __shared__ int bad;
    if (threadIdx.x == 0) bad = 0;
    __syncthreads();
    const unsigned short* u = (const unsigned short*)x;
    int mybad = 0;
    for (int k = 0; k < 16; ++k) {
        size_t i = (size_t)(threadIdx.x + k * 256) * 1987 + 3;
        float v = bf2f(u[2 * i]);
        if (!(fabsf(v) < 1000.0f)) mybad = 1;
    }
    if (mybad) atomicOr(&bad, 1);
    __syncthreads();
    if (threadIdx.x == 0) *flag = (bad == 0) ? 1 : 0;
}

// ---------------- one-time setup ----------------

// WB: fragment-contiguous bf16 weights.
// Element (cs, w, ni, ks, lane, e) = W^T[col][k],
//   col = ni*512 + cs*16 + (lane&15),  k = w*384 + ks*32 + (lane>>4)*8 + e
// at flat index ((cs*4 + w)*48 + ni*12 + ks)*512 + lane*8 + e.
// k<512 -> Wx, <1024 -> Wh, else Wattn (row-major [k][2048]).
__global__ __launch_bounds__(256) void build_wB(const void* __restrict__ Wx,
                                                const void* __restrict__ Wh,
                                                const void* __restrict__ Wattn,
                                                const int* __restrict__ flagp,
                                                unsigned short* __restrict__ WB) {
    int isbf = *flagp;
    int cs = blockIdx.x;          // 0..31
    int w  = blockIdx.y;          // 0..3
    int tid = threadIdx.x;
    int ni = tid >> 6;            // 0..3 (gate)
    int l  = tid & 63;
    int col = ni * 512 + cs * 16 + (l & 15);
    int kr  = (l >> 4) * 8;
    unsigned short* dst = WB
        + (size_t)((cs * 4 + w) * 48 + ni * 12) * 512 + l * 8;
#pragma unroll 1
    for (int ks = 0; ks < 12; ++ks) {
        int k0 = w * 384 + ks * 32 + kr;   // multiple of 8; 8-group stays in one region
        unsigned short v[8];
#pragma unroll
        for (int e = 0; e < 8; ++e) {
            int k = k0 + e;
            const void* s; size_t off;
            if (k < 512)       { s = Wx;    off = (size_t)k * 2048 + col; }
            else if (k < 1024) { s = Wh;    off = (size_t)(k - 512) * 2048 + col; }
            else               { s = Wattn; off = (size_t)(k - 1024) * 2048 + col; }
            v[e] = f2bf(ldin(s, off, isbf));
        }
        *(ushort4*)(dst + (size_t)ks * 512)     = *(ushort4*)&v[0];
        *(ushort4*)(dst + (size_t)ks * 512 + 4) = *(ushort4*)&v[4];
    }
}

// h0 = c0 = mean over 16 spatial positions of A[n,h,:,:]
__global__ __launch_bounds__(256) void init_state(const void* __restrict__ A,
                                                  const int* __restrict__ flagp,
                                                  float* __restrict__ h,
                                                  float* __restrict__ c) {
    int isbf = *flagp;
    int n = blockIdx.x;
    int tid = threadIdx.x;
#pragma unroll
    for (int j = 0; j < 2; ++j) {
        int hh = tid * 2 + j;
        size_t base = ((size_t)n * 512 + hh) * 16;
        float s = 0.f;
#pragma unroll
        for (int p = 0; p < 16; ++p) s += ldin(A, base + p, isbf);
        s *= (1.0f / 16.0f);
        h[n * 512 + hh] = s;
        c[n * 512 + hh] = s;
    }
}

// ---------------- per-step kernel 1: prep (attention + Acat) ----------------
// 256 blocks x 256 threads; block b preps rows 2b, 2b+1 (128 threads/row).
__global__ __launch_bounds__(256) void prep_step(const void* __restrict__ x,
                                                 const void* __restrict__ A,
                                                 const int* __restrict__ flagp,
                                                 const float* __restrict__ h,
                                                 unsigned short* __restrict__ Ahi,
                                                 unsigned short* __restrict__ Alo,
                                                 int t) {
    const int isbf = *flagp;
    const int tid  = threadIdx.x;
    const int lane = tid & 63;
    const int wave = tid >> 6;
    const int bid  = blockIdx.x;
    __shared__ float wsum[4][16];

    const int prow = tid >> 7;          // 0..1
    const int ptl  = tid & 127;         // 128 threads per row
    const int pn   = bid * 2 + prow;
    const int he0  = ptl * 4;           // 4 consecutive h per thread

    // A[pn][he0+e][p] as packed bf16 pairs (8 u32 per e)
    unsigned apk[4][8];
    if (isbf) {
        const uint4* ap = (const uint4*)((const unsigned short*)A
                                         + ((size_t)pn * 512 + he0) * 16);
#pragma unroll
        for (int e = 0; e < 4; ++e) {
            uint4 a = ap[2 * e], b = ap[2 * e + 1];
            apk[e][0] = a.x; apk[e][1] = a.y; apk[e][2] = a.z; apk[e][3] = a.w;
            apk[e][4] = b.x; apk[e][5] = b.y; apk[e][6] = b.z; apk[e][7] = b.w;
        }
    } else {
        const float* ap = (const float*)A + ((size_t)pn * 512 + he0) * 16;
#pragma unroll
        for (int e = 0; e < 4; ++e)
#pragma unroll
            for (int q = 0; q < 8; ++q)
                apk[e][q] = (unsigned)f2bf(ap[e * 16 + 2 * q])
                          | ((unsigned)f2bf(ap[e * 16 + 2 * q + 1]) << 16);
    }

    float4 hq = *(const float4*)&h[(size_t)pn * 512 + he0];
    float hv[4] = { hq.x, hq.y, hq.z, hq.w };

    float part[16];
#pragma unroll
    for (int p = 0; p < 16; ++p) part[p] = 0.f;
#pragma unroll
    for (int e = 0; e < 4; ++e)
#pragma unroll
        for (int q = 0; q < 8; ++q) {
            unsigned u = apk[e][q];
            union { unsigned u; float f; } lo, hi;
            lo.u = u << 16; hi.u = u & 0xffff0000u;
            part[2 * q]     += hv[e] * lo.f;
            part[2 * q + 1] += hv[e] * hi.f;
        }
#pragma unroll
    for (int off = 32; off > 0; off >>= 1)
#pragma unroll
        for (int p = 0; p < 16; ++p) part[p] += __shfl_down(part[p], off, 64);
    if (lane == 0)
#pragma unroll
        for (int p = 0; p < 16; ++p) wsum[wave][p] = part[p];
    __syncthreads();

    const float scale = 0.04419417382415922f;  // 1/sqrt(512)
    float sc[16], mx = -1e30f;
#pragma unroll
    for (int p = 0; p < 16; ++p) {
        sc[p] = (wsum[prow * 2][p] + wsum[prow * 2 + 1][p]) * scale;
        mx = fmaxf(mx, sc[p]);
    }
    float ssum = 0.f;
#pragma unroll
    for (int p = 0; p < 16; ++p) { sc[p] = __expf(sc[p] - mx); ssum += sc[p]; }
    const float inv = 1.0f / ssum;

    float at[4];
#pragma unroll
    for (int e = 0; e < 4; ++e) {
        float s = 0.f;
#pragma unroll
        for (int q = 0; q < 8; ++q) {
            unsigned u = apk[e][q];
            union { unsigned u; float f; } lo, hi;
            lo.u = u << 16; hi.u = u & 0xffff0000u;
            s += lo.f * sc[2 * q] + hi.f * sc[2 * q + 1];
        }
        at[e] = s * inv;
    }

    unsigned short* hrow = Ahi + (size_t)pn * KTOT;
    unsigned short* lrow = Alo + (size_t)pn * KTOT;
    // x region (k 0..511): only needed in Acat for fp32 inputs
    // (bf16 path stages x chunks directly from x in gemm_step).
    if (!isbf) {
        const float* xp = (const float*)x + ((size_t)pn * TS + t) * 512 + he0;
        ushort4 v = { f2bf(xp[0]), f2bf(xp[1]), f2bf(xp[2]), f2bf(xp[3]) };
        *(ushort4*)&hrow[he0] = v;
    }
    // h region (k 512..1023) hi+lo
    {
        ushort4 hiv, lov;
#pragma unroll
        for (int e = 0; e < 4; ++e) {
            unsigned short hb = f2bf(hv[e]);
            hiv[e] = hb; lov[e] = f2bf(hv[e] - bf2f(hb));
        }
        *(ushort4*)&hrow[512 + he0] = hiv;
        *(ushort4*)&lrow[512 + he0] = lov;
    }
    // attn region (k 1024..1535) hi+lo
    {
        ushort4 hiv, lov;
#pragma unroll
        for (int e = 0; e < 4; ++e) {
            unsigned short hb = f2bf(at[e]);
            hiv[e] = hb; lov[e] = f2bf(at[e] - bf2f(hb));
        }
        *(ushort4*)&hrow[1024 + he0] = hiv;
        *(ushort4*)&lrow[1024 + he0] = lov;
    }
}

// ---------------- staging helpers ----------------

__device__ __forceinline__ void gload_lds16(const void* g, void* l) {
    __builtin_amdgcn_global_load_lds(
        (const __attribute__((address_space(1))) void*)g,
        (__attribute__((address_space(3))) void*)l, 16, 0, 0);
}

// Stage one 64-row x 64-elem chunk (8 KB) into `slot`, LDS order
// [ksub2][mi4][lane16B] so frag reads are base + lane*16 (conflict-free).
// src (Acat layout, row stride 3072 B) already includes:
//   array base + n0*3072 + (lane&15)*3072 + (lane>>4)*16 + kbase*2.
__device__ __forceinline__ void stage8(const char* src, char* slot) {
#pragma unroll
    for (int j = 0; j < 8; ++j)
        gload_lds16(src + (size_t)((j & 3) * 49152 + (j >> 2) * 64),
                    slot + j * 1024);
}

// Same, sourcing from x directly (bf16 input; row stride 64*512*2 B).
// src includes: x base + (n0+(lane&15))*65536 + t*1024 + (lane>>4)*16 + kbase*2.
__device__ __forceinline__ void stage8x(const char* src, char* slot) {
#pragma unroll
    for (int j = 0; j < 8; ++j)
        gload_lds16(src + (size_t)((j & 3) * 1048576 + (j >> 2) * 64),
                    slot + j * 1024);
}

// ---------------- per-step kernel 2: GEMM + LSTM epilogue ----------------
// 256 blocks x 256 threads, ~128 KB LDS -> 1 block/CU.
// XCD-rectangle mapping (bid->XCD is bid%8 round-robin; perf-only heuristic):
//   g = bid&7 (XCD), j = bid>>3; m = (g>>2)*4 + (j>>3); cs = (g&3)*8 + (j&7).
// Each XCD hosts m in one 4-tile half and cs in one 8-slice band, so B
// slices (shared by 8 blocks) and Acat tiles (shared by 32) re-use the
// XCD's own L2 despite the per-launch invalidate.
// wave w: K-range [384w, 384w+384) for ALL 4 gates; B slice in 192 VGPRs.
__global__ __launch_bounds__(256, 1) void gemm_step(
    const void* __restrict__ x, const unsigned short* __restrict__ WB,
    const void* __restrict__ bias, const int* __restrict__ flagp,
    float* __restrict__ h, float* __restrict__ c,
    const unsigned short* __restrict__ Ahi, const unsigned short* __restrict__ Alo,
    void* __restrict__ out, int t)
{
    const int isbf = *flagp;
    const int tid  = threadIdx.x;
    const int lane = tid & 63;
    const int wave = tid >> 6;
    const int bid  = blockIdx.x;
    const int g    = bid & 7;
    const int j_   = bid >> 3;
    const int m    = ((g >> 2) << 2) | (j_ >> 3);
    const int cs   = ((g & 3) << 3) | (j_ & 7);
    const int n0   = m * 64;

    __shared__ __align__(16) char ring[131072];   // 4 waves x 2 slots x (8K hi + 8K lo)

    // ---- epilogue constants + c slab (per launch) ----
    const int ecol  = tid & 15;
    const int erow0 = (tid >> 4) * 4;
    const int hcol  = cs * 16 + ecol;
    const float bi  = ldin(bias, hcol,        isbf);
    const float bf_ = ldin(bias, 512 + hcol,  isbf);
    const float bo  = ldin(bias, 1024 + hcol, isbf);
    const float bg  = ldin(bias, 1536 + hcol, isbf);
    float cst[4];
#pragma unroll
    for (int j = 0; j < 4; ++j)
        cst[j] = c[(size_t)(n0 + erow0 + j) * 512 + hcol];

    // ---- B fragments (48 x bf16x8 = 192 VGPR), coalesced from WB ----
    const int kw0 = wave * 384;
    bf16x8 Bb[48];
    {
        const unsigned short* wb = WB
            + (size_t)((cs * 4 + wave) * 48) * 512 + lane * 8;
#pragma unroll
        for (int f = 0; f < 48; ++f)
            Bb[f] = *(const bf16x8*)(wb + (size_t)f * 512);
    }
    // NO drain: B fetch overlaps the staging prologue. The sched_barrier
    // keeps all B loads issued BEFORE any staging DMA, so the K-loop's
    // counted vmcnt (which waits down to ops(next chunk)) also implies B
    // completion (B ops are strictly older than stage0's DMAs). The
    // compiler additionally inserts its own waits before Bb's first MFMA use.
    __builtin_amdgcn_sched_barrier(0);

    // per-wave staging pointers
    char* const slH[2] = { ring + wave * 32768,         ring + wave * 32768 + 8192 };
    char* const slL[2] = { ring + wave * 32768 + 16384, ring + wave * 32768 + 24576 };
    const size_t laneoff = (size_t)((lane & 15) * 3072 + (lane >> 4) * 16);
    const char* const srcH = (const char*)Ahi + (size_t)n0 * 3072 + laneoff;
    const char* const srcL = (const char*)Alo + (size_t)n0 * 3072 + laneoff;
    const char* const xrow = (const char*)x
        + (size_t)(n0 + (lane & 15)) * 65536 + (size_t)((lane >> 4) * 16);
    const char* const xsrc = xrow + (size_t)t * 1024;
    float* const accX = (float*)ring;   // [4][64][64] f32, reuses ring post-GEMM

    // ---- prologue staging: chunks 0,1 of this wave's K-range ----
    if (isbf && kw0 < 512) stage8x(xsrc + (size_t)kw0 * 2, slH[0]);
    else {
        stage8(srcH + (size_t)kw0 * 2, slH[0]);
        if (kw0 >= 512) stage8(srcL + (size_t)kw0 * 2, slL[0]);
    }
    {
        const int kb1 = kw0 + 64;
        if (isbf && kb1 < 512) stage8x(xsrc + (size_t)kb1 * 2, slH[1]);
        else {
            stage8(srcH + (size_t)kb1 * 2, slH[1]);
            if (kb1 >= 512) stage8(srcL + (size_t)kb1 * 2, slL[1]);
        }
    }

    // ---- K-split GEMM, per-wave double-buffered pipeline ----
    f32x4 acc[4][4];   // [mi][ni]
#pragma unroll
    for (int mi = 0; mi < 4; ++mi)
#pragma unroll
        for (int ni = 0; ni < 4; ++ni) acc[mi][ni] = (f32x4){0.f, 0.f, 0.f, 0.f};

#pragma unroll
    for (int i = 0; i < 6; ++i) {
        // wave-exact counted wait: chunk i retired <=> vmcnt(ops(chunk i+1))
        if (i < 5) {
            if (kw0 + (i + 1) * 64 < 512)
                asm volatile("s_waitcnt vmcnt(8)" ::: "memory");
            else
                asm volatile("s_waitcnt vmcnt(16)" ::: "memory");
        } else {
            asm volatile("s_waitcnt vmcnt(0)" ::: "memory");
        }
        __builtin_amdgcn_sched_barrier(0);
        const int kbase = kw0 + i * 64;
        const bool xc = (kbase < 512);     // wave-uniform
        char* sH = slH[i & 1];
        char* sL = slL[i & 1];
        bf16x8 ah0[4], ah1[4], al0[4], al1[4];
#pragma unroll
        for (int mi = 0; mi < 4; ++mi) {
            ah0[mi] = *(const bf16x8*)(sH + mi * 1024 + lane * 16);
            ah1[mi] = *(const bf16x8*)(sH + 4096 + mi * 1024 + lane * 16);
        }
        if (!xc) {
#pragma unroll
            for (int mi = 0; mi < 4; ++mi) {
                al0[mi] = *(const bf16x8*)(sL + mi * 1024 + lane * 16);
                al1[mi] = *(const bf16x8*)(sL + 4096 + mi * 1024 + lane * 16);
            }
        }
        // all ds_reads of this slot done before its DMA overwrite issues
        asm volatile("s_waitcnt lgkmcnt(0)" ::: "memory");
        __builtin_amdgcn_sched_barrier(0);
        if (i < 4) {
            const int nkb = kw0 + (i + 2) * 64;
            if (isbf && nkb < 512) {
                stage8x(xsrc + (size_t)nkb * 2, slH[i & 1]);
            } else {
                stage8(srcH + (size_t)nkb * 2, slH[i & 1]);
                if (nkb >= 512) stage8(srcL + (size_t)nkb * 2, slL[i & 1]);
            }
        }
        __builtin_amdgcn_sched_barrier(0);
#pragma unroll
        for (int ni = 0; ni < 4; ++ni)
#pragma unroll
            for (int mi = 0; mi < 4; ++mi)
                acc[mi][ni] = __builtin_amdgcn_mfma_f32_16x16x32_bf16(
                    ah0[mi], Bb[ni * 12 + i * 2], acc[mi][ni], 0, 0, 0);
#pragma unroll
        for (int ni = 0; ni < 4; ++ni)
#pragma unroll
            for (int mi = 0; mi < 4; ++mi)
                acc[mi][ni] = __builtin_amdgcn_mfma_f32_16x16x32_bf16(
                    ah1[mi], Bb[ni * 12 + i * 2 + 1], acc[mi][ni], 0, 0, 0);
        if (!xc) {
#pragma unroll
            for (int ni = 0; ni < 4; ++ni)
#pragma unroll
                for (int mi = 0; mi < 4; ++mi)
                    acc[mi][ni] = __builtin_amdgcn_mfma_f32_16x16x32_bf16(
                        al0[mi], Bb[ni * 12 + i * 2], acc[mi][ni], 0, 0, 0);
#pragma unroll
            for (int ni = 0; ni < 4; ++ni)
#pragma unroll
                for (int mi = 0; mi < 4; ++mi)
                    acc[mi][ni] = __builtin_amdgcn_mfma_f32_16x16x32_bf16(
                        al1[mi], Bb[ni * 12 + i * 2 + 1], acc[mi][ni], 0, 0, 0);
        }
    }

    // ---- cross-wave K-reduce through LDS (ring reused as accX) ----
    __syncthreads();
#pragma unroll
    for (int mi = 0; mi < 4; ++mi)
#pragma unroll
        for (int ni = 0; ni < 4; ++ni)
#pragma unroll
            for (int r = 0; r < 4; ++r)
                accX[wave * 4096
                     + (mi * 16 + (lane >> 4) * 4 + r) * 64
                     + ni * 16 + (lane & 15)] = acc[mi][ni][r];
    __syncthreads();

    // ---- fused LSTM epilogue ----
#pragma unroll
    for (int j = 0; j < 4; ++j) {
        const int r = erow0 + j;
        const int n = n0 + r;
        float s[4];
#pragma unroll
        for (int gi = 0; gi < 4; ++gi) {
            const int base = r * 64 + gi * 16 + ecol;
            s[gi] = accX[base] + accX[4096 + base]
                  + accX[8192 + base] + accX[12288 + base];
        }
        const float xi = s[0] + bi;
        const float xf = s[1] + bf_;
        const float xo = s[2] + bo;
        const float xg = s[3] + bg;
        const float iv = 1.f / (1.f + __expf(-xi));
        const float fv = 1.f / (1.f + __expf(-xf));
        const float ov = 1.f / (1.f + __expf(-xo));
        const float gv = 1.f - 2.f / (__expf(2.f * xg) + 1.f);     // tanh
        const float cnew = fv * cst[j] + iv * gv;
        const float tc = 1.f - 2.f / (__expf(2.f * cnew) + 1.f);   // tanh
        const float hnew = ov * tc;
        c[(size_t)n * 512 + hcol] = cnew;
        h[(size_t)n * 512 + hcol] = hnew;
        const size_t oidx = ((size_t)n * TS + t) * 512 + hcol;
        if (isbf) ((__hip_bfloat16*)out)[oidx] = __float2bfloat16(hnew);
        else      ((float*)out)[oidx] = hnew;
    }
}

// ---------------- launch ----------------

extern "C" void kernel_launch(void* const* d_in, const int* in_sizes, int n_in,
                              void* d_out, int out_size, void* d_ws, size_t ws_size,
                              hipStream_t stream) {
    const void* x     = d_in[0];
    const void* A     = d_in[1];
    const void* Wx    = d_in[2];
    const void* Wh    = d_in[3];
    const void* Wattn = d_in[4];
    const void* bias  = d_in[5];

    char* ws = (char*)d_ws;
    const size_t WSZ = (size_t)2048 * KTOT * 2;   // 6291456 B
    const size_t ASZ = (size_t)NBATCH * KTOT * 2; // 1572864 B
    unsigned short* WB  = (unsigned short*)ws;
    unsigned short* Ahi = (unsigned short*)(ws + WSZ);
    unsigned short* Alo = (unsigned short*)(ws + WSZ + ASZ);
    float* hbuf = (float*)(ws + WSZ + 2 * ASZ);
    float* cbuf = (float*)(ws + WSZ + 2 * ASZ + 1048576);
    int* flag   = (int*)(ws + WSZ + 2 * ASZ + 2 * 1048576);

    detect_dtype<<<1, 256, 0, stream>>>(x, flag);
    build_wB<<<dim3(32, 4), 256, 0, stream>>>(Wx, Wh, Wattn, flag, WB);
    init_state<<<512, 256, 0, stream>>>(A, flag, hbuf, cbuf);
    for (int t = 0; t < TS; ++t) {
        prep_step<<<256, 256, 0, stream>>>(x, A, flag, hbuf, Ahi, Alo, t);
        gemm_step<<<256, 256, 0, stream>>>(x, WB, bias, flag, hbuf, cbuf,
                                           Ahi, Alo, d_out, t);
    }
}